// Round 1
// baseline (976.197 us; speedup 1.0000x reference)
//
#include <hip/hip_runtime.h>

#define B_SZ 8192
#define M_SZ 256
#define N_SZ 512
#define TB 32
#define LDP 520   // padded f16 row stride for state buffers (16B-aligned rows)
#define LDPY 264  // padded f16 row stride for y staging
#define NITER 16

typedef _Float16 half8 __attribute__((ext_vector_type(8)));
typedef float floatx4 __attribute__((ext_vector_type(4)));

__global__ void prep_kernel(const float* __restrict__ S, const float* __restrict__ W,
                            const float* __restrict__ D,
                            _Float16* __restrict__ Sf, _Float16* __restrict__ Wf,
                            _Float16* __restrict__ Df, _Float16* __restrict__ Dtf) {
  int i = blockIdx.x * blockDim.x + threadIdx.x;
  if (i < N_SZ * N_SZ) {
    Sf[i] = (_Float16)S[i];
    float d = D[i];
    Df[i] = (_Float16)d;
    int r = i >> 9;
    int c = i & (N_SZ - 1);
    Dtf[c * N_SZ + r] = (_Float16)d;  // Dt[c][r] = D[r][c]
  }
  if (i < N_SZ * M_SZ) Wf[i] = (_Float16)W[i];
}

__global__ __launch_bounds__(512, 2) void ista_kernel(
    const float* __restrict__ y, const _Float16* __restrict__ Sf,
    const _Float16* __restrict__ Df, const _Float16* __restrict__ Dtf,
    const _Float16* __restrict__ Wf, const float* __restrict__ thrp,
    float* __restrict__ out) {
  __shared__ _Float16 bufA[TB * LDP];
  __shared__ _Float16 bufB[TB * LDP];
  __shared__ _Float16 ybuf[TB * LDPY];

  const int tid = threadIdx.x;
  const int wave = tid >> 6;       // 0..7
  const int lane = tid & 63;
  const int m16 = lane & 15;       // A row in tile / B col in tile
  const int q = lane >> 4;         // 0..3
  const int rowBase = blockIdx.x * TB;
  const int colBase = wave * 64;   // each wave: 4 col-tiles of 16 = 64 cols

  // ---- stage y rows -> ybuf (f16) ----
  {
    const int r = tid >> 4;              // 0..31
    const int c0 = (tid & 15) << 4;      // 0,16,...,240
    const float* src = y + (size_t)(rowBase + r) * M_SZ + c0;
#pragma unroll
    for (int j = 0; j < 16; j += 4) {
      float4 v = *reinterpret_cast<const float4*>(src + j);
      _Float16* dst = &ybuf[r * LDPY + c0 + j];
      dst[0] = (_Float16)v.x;
      dst[1] = (_Float16)v.y;
      dst[2] = (_Float16)v.z;
      dst[3] = (_Float16)v.w;
    }
  }
  // ---- zero d state ----
  for (int i = tid; i < TB * LDP; i += 512) bufA[i] = (_Float16)0.f;
  // ---- zero output slice 0 (d0 = 0) ----
  {
    float4 z4 = {0.f, 0.f, 0.f, 0.f};
    float4* o4 = reinterpret_cast<float4*>(out + (size_t)rowBase * N_SZ);
    for (int i = tid; i < TB * N_SZ / 4; i += 512) o4[i] = z4;
  }
  __syncthreads();

  // ---- Wy = y @ W^T (K=256), kept in fp32 registers ----
  floatx4 wy[2][4];
#pragma unroll
  for (int rt = 0; rt < 2; ++rt)
#pragma unroll
    for (int ct = 0; ct < 4; ++ct) wy[rt][ct] = (floatx4){0.f, 0.f, 0.f, 0.f};

#pragma unroll 2
  for (int ks = 0; ks < M_SZ / 32; ++ks) {
    half8 a0 = *reinterpret_cast<const half8*>(&ybuf[m16 * LDPY + ks * 32 + q * 8]);
    half8 a1 = *reinterpret_cast<const half8*>(&ybuf[(16 + m16) * LDPY + ks * 32 + q * 8]);
#pragma unroll
    for (int ct = 0; ct < 4; ++ct) {
      const int n = colBase + ct * 16 + m16;
      half8 b = *reinterpret_cast<const half8*>(Wf + n * M_SZ + ks * 32 + q * 8);
      wy[0][ct] = __builtin_amdgcn_mfma_f32_16x16x32_f16(a0, b, wy[0][ct], 0, 0, 0);
      wy[1][ct] = __builtin_amdgcn_mfma_f32_16x16x32_f16(a1, b, wy[1][ct], 0, 0, 0);
    }
  }

  const float thrv = *thrp;

  // K=512 GEMM over LDS A-buffer with B-fragments straight from global (L2-hot)
  auto gemm_step = [&](const _Float16* Abuf, const _Float16* __restrict__ Bmat,
                       floatx4 (*acc)[4]) {
#pragma unroll 4
    for (int ks = 0; ks < N_SZ / 32; ++ks) {
      half8 a0 = *reinterpret_cast<const half8*>(Abuf + m16 * LDP + ks * 32 + q * 8);
      half8 a1 = *reinterpret_cast<const half8*>(Abuf + (16 + m16) * LDP + ks * 32 + q * 8);
#pragma unroll
      for (int ct = 0; ct < 4; ++ct) {
        const int n = colBase + ct * 16 + m16;
        half8 b = *reinterpret_cast<const half8*>(Bmat + n * N_SZ + ks * 32 + q * 8);
        acc[0][ct] = __builtin_amdgcn_mfma_f32_16x16x32_f16(a0, b, acc[0][ct], 0, 0, 0);
        acc[1][ct] = __builtin_amdgcn_mfma_f32_16x16x32_f16(a1, b, acc[1][ct], 0, 0, 0);
      }
    }
  };

  _Float16* dbuf = bufA;
  _Float16* zbuf = bufB;

#pragma unroll 1
  for (int it = 1; it <= NITER; ++it) {
    floatx4 acc[2][4];

    // ---- GEMM1: z = d @ S^T + Wy ----
#pragma unroll
    for (int rt = 0; rt < 2; ++rt)
#pragma unroll
      for (int ct = 0; ct < 4; ++ct) acc[rt][ct] = wy[rt][ct];
    gemm_step(dbuf, Sf, acc);
#pragma unroll
    for (int rt = 0; rt < 2; ++rt)
#pragma unroll
      for (int ct = 0; ct < 4; ++ct)
#pragma unroll
        for (int r = 0; r < 4; ++r)
          zbuf[(rt * 16 + q * 4 + r) * LDP + colBase + ct * 16 + m16] =
              (_Float16)acc[rt][ct][r];
    __syncthreads();

    // ---- GEMM2: u = z @ D^T ; s = soft_thr(u) -> dbuf ----
#pragma unroll
    for (int rt = 0; rt < 2; ++rt)
#pragma unroll
      for (int ct = 0; ct < 4; ++ct) acc[rt][ct] = (floatx4){0.f, 0.f, 0.f, 0.f};
    gemm_step(zbuf, Df, acc);
#pragma unroll
    for (int rt = 0; rt < 2; ++rt)
#pragma unroll
      for (int ct = 0; ct < 4; ++ct)
#pragma unroll
        for (int r = 0; r < 4; ++r) {
          float u = acc[rt][ct][r];
          float s = fmaxf(u - thrv, 0.f) - fmaxf(-u - thrv, 0.f);
          dbuf[(rt * 16 + q * 4 + r) * LDP + colBase + ct * 16 + m16] = (_Float16)s;
        }
    __syncthreads();

    // ---- GEMM3: d_new = s @ D  (= s @ Dt^T) -> zbuf + out slice ----
#pragma unroll
    for (int rt = 0; rt < 2; ++rt)
#pragma unroll
      for (int ct = 0; ct < 4; ++ct) acc[rt][ct] = (floatx4){0.f, 0.f, 0.f, 0.f};
    gemm_step(dbuf, Dtf, acc);
    float* oslice = out + ((size_t)it * B_SZ + rowBase) * N_SZ;
#pragma unroll
    for (int rt = 0; rt < 2; ++rt)
#pragma unroll
      for (int ct = 0; ct < 4; ++ct)
#pragma unroll
        for (int r = 0; r < 4; ++r) {
          float v = acc[rt][ct][r];
          const int row = rt * 16 + q * 4 + r;
          const int col = colBase + ct * 16 + m16;
          zbuf[row * LDP + col] = (_Float16)v;
          oslice[(size_t)row * N_SZ + col] = v;
        }
    __syncthreads();

    _Float16* tmp = dbuf;
    dbuf = zbuf;
    zbuf = tmp;
  }
}

extern "C" void kernel_launch(void* const* d_in, const int* in_sizes, int n_in,
                              void* d_out, int out_size, void* d_ws, size_t ws_size,
                              hipStream_t stream) {
  const float* y = (const float*)d_in[0];
  const float* S = (const float*)d_in[1];
  const float* W = (const float*)d_in[2];
  const float* D = (const float*)d_in[3];
  const float* thr = (const float*)d_in[4];
  float* out = (float*)d_out;

  char* ws = (char*)d_ws;
  _Float16* Sf = (_Float16*)(ws);
  _Float16* Df = (_Float16*)(ws + 512 * 1024);
  _Float16* Dtf = (_Float16*)(ws + 1024 * 1024);
  _Float16* Wf = (_Float16*)(ws + 1536 * 1024);

  prep_kernel<<<(N_SZ * N_SZ + 255) / 256, 256, 0, stream>>>(S, W, D, Sf, Wf, Df, Dtf);
  ista_kernel<<<B_SZ / TB, 512, 0, stream>>>(y, Sf, Df, Dtf, Wf, thr, out);
}

// Round 2
// 845.394 us; speedup vs baseline: 1.1547x; 1.1547x over previous
//
#include <hip/hip_runtime.h>

#define B_SZ 8192
#define M_SZ 256
#define N_SZ 512
#define TB 64
#define THREADS 1024
#define LDP 520   // padded f16 row stride (16B-aligned rows, stride%32dw==4 -> 2-way-free reads)
#define LDPY 264  // padded f16 row stride for y staging
#define NITER 16

typedef _Float16 half8 __attribute__((ext_vector_type(8)));
typedef _Float16 half4 __attribute__((ext_vector_type(4)));
typedef float floatx4 __attribute__((ext_vector_type(4)));

// ---- f16 conversions of D, D^T, W ----
__global__ void conv_kernel(const float* __restrict__ W, const float* __restrict__ D,
                            _Float16* __restrict__ Wf, _Float16* __restrict__ Df,
                            _Float16* __restrict__ Dtf) {
  int i = blockIdx.x * blockDim.x + threadIdx.x;
  if (i < N_SZ * N_SZ) {
    float d = D[i];
    Df[i] = (_Float16)d;
    int r = i >> 9;
    int c = i & (N_SZ - 1);
    Dtf[c * N_SZ + r] = (_Float16)d;
  }
  if (i < N_SZ * M_SZ) Wf[i] = (_Float16)W[i];
}

// ---- E = D @ S  (fp32 accumulate, f16 output) ----
__global__ __launch_bounds__(256) void ecomp_kernel(const float* __restrict__ S,
                                                    const float* __restrict__ D,
                                                    _Float16* __restrict__ Ef) {
  __shared__ float Dst[8 * N_SZ];
  const int tid = threadIdx.x;
  const int r0 = blockIdx.x * 8;
  for (int i = tid; i < 8 * N_SZ; i += 256) Dst[i] = D[(size_t)r0 * N_SZ + i];
  __syncthreads();
  float acc[8][2];
#pragma unroll
  for (int r = 0; r < 8; ++r) acc[r][0] = acc[r][1] = 0.f;
#pragma unroll 4
  for (int j = 0; j < N_SZ; ++j) {
    float s0 = S[(size_t)j * N_SZ + tid];
    float s1 = S[(size_t)j * N_SZ + tid + 256];
#pragma unroll
    for (int r = 0; r < 8; ++r) {
      float dv = Dst[r * N_SZ + j];
      acc[r][0] += dv * s0;
      acc[r][1] += dv * s1;
    }
  }
#pragma unroll
  for (int r = 0; r < 8; ++r) {
    Ef[(size_t)(r0 + r) * N_SZ + tid] = (_Float16)acc[r][0];
    Ef[(size_t)(r0 + r) * N_SZ + tid + 256] = (_Float16)acc[r][1];
  }
}

__global__ __launch_bounds__(THREADS) void ista_kernel(
    const float* __restrict__ y, const _Float16* __restrict__ Ef,
    const _Float16* __restrict__ Df, const _Float16* __restrict__ Dtf,
    const _Float16* __restrict__ Wf, const float* __restrict__ thrp,
    float* __restrict__ out) {
  __shared__ _Float16 bufA[TB * LDP];  // d-state (initially: y staging)
  __shared__ _Float16 bufB[TB * LDP];  // s scratch (initially: Wy)

  const int tid = threadIdx.x;
  const int wave = tid >> 6;        // 0..15
  const int lane = tid & 63;
  const int m16 = lane & 15;
  const int q = lane >> 4;          // 0..3
  const int rowBase = blockIdx.x * TB;
  const int colBase = wave * 32;    // 2 col-tiles of 16 per wave

  // ---- stage y rows -> bufA (f16, stride LDPY) ----
  {
    const int r = tid >> 4;              // 0..63
    const int c0 = (tid & 15) << 4;      // 0..240
    const float* src = y + (size_t)(rowBase + r) * M_SZ + c0;
#pragma unroll
    for (int j = 0; j < 16; j += 4) {
      float4 v = *reinterpret_cast<const float4*>(src + j);
      _Float16* dst = &bufA[r * LDPY + c0 + j];
      dst[0] = (_Float16)v.x;
      dst[1] = (_Float16)v.y;
      dst[2] = (_Float16)v.z;
      dst[3] = (_Float16)v.w;
    }
  }
  __syncthreads();

  floatx4 acc[4][2];

  // ---- Wy = y @ W^T (K=256) ----
#pragma unroll
  for (int rt = 0; rt < 4; ++rt) acc[rt][0] = acc[rt][1] = (floatx4){0.f, 0.f, 0.f, 0.f};
#pragma unroll 2
  for (int ks = 0; ks < M_SZ / 32; ++ks) {
    half8 a0 = *reinterpret_cast<const half8*>(&bufA[m16 * LDPY + ks * 32 + q * 8]);
    half8 a1 = *reinterpret_cast<const half8*>(&bufA[(16 + m16) * LDPY + ks * 32 + q * 8]);
    half8 a2 = *reinterpret_cast<const half8*>(&bufA[(32 + m16) * LDPY + ks * 32 + q * 8]);
    half8 a3 = *reinterpret_cast<const half8*>(&bufA[(48 + m16) * LDPY + ks * 32 + q * 8]);
#pragma unroll
    for (int ct = 0; ct < 2; ++ct) {
      half8 b = *reinterpret_cast<const half8*>(Wf + (size_t)(colBase + ct * 16 + m16) * M_SZ + ks * 32 + q * 8);
      acc[0][ct] = __builtin_amdgcn_mfma_f32_16x16x32_f16(a0, b, acc[0][ct], 0, 0, 0);
      acc[1][ct] = __builtin_amdgcn_mfma_f32_16x16x32_f16(a1, b, acc[1][ct], 0, 0, 0);
      acc[2][ct] = __builtin_amdgcn_mfma_f32_16x16x32_f16(a2, b, acc[2][ct], 0, 0, 0);
      acc[3][ct] = __builtin_amdgcn_mfma_f32_16x16x32_f16(a3, b, acc[3][ct], 0, 0, 0);
    }
  }
  // write Wy -> bufB
#pragma unroll
  for (int rt = 0; rt < 4; ++rt)
#pragma unroll
    for (int ct = 0; ct < 2; ++ct)
#pragma unroll
      for (int r = 0; r < 4; ++r)
        bufB[(rt * 16 + q * 4 + r) * LDP + colBase + ct * 16 + m16] = (_Float16)acc[rt][ct][r];
  __syncthreads();

  // K=512 GEMM: A from LDS, B from global (L2-hot)
  auto gemmK512 = [&](const _Float16* Abuf, const _Float16* __restrict__ Bmat) {
    const _Float16* arow = Abuf + m16 * LDP + q * 8;
    const _Float16* brow0 = Bmat + (size_t)(colBase + m16) * N_SZ + q * 8;
    const _Float16* brow1 = Bmat + (size_t)(colBase + 16 + m16) * N_SZ + q * 8;
#pragma unroll 2
    for (int ks = 0; ks < N_SZ / 32; ++ks) {
      half8 a0 = *reinterpret_cast<const half8*>(arow + ks * 32);
      half8 a1 = *reinterpret_cast<const half8*>(arow + 16 * LDP + ks * 32);
      half8 a2 = *reinterpret_cast<const half8*>(arow + 32 * LDP + ks * 32);
      half8 a3 = *reinterpret_cast<const half8*>(arow + 48 * LDP + ks * 32);
      half8 b0 = *reinterpret_cast<const half8*>(brow0 + ks * 32);
      half8 b1 = *reinterpret_cast<const half8*>(brow1 + ks * 32);
      acc[0][0] = __builtin_amdgcn_mfma_f32_16x16x32_f16(a0, b0, acc[0][0], 0, 0, 0);
      acc[0][1] = __builtin_amdgcn_mfma_f32_16x16x32_f16(a0, b1, acc[0][1], 0, 0, 0);
      acc[1][0] = __builtin_amdgcn_mfma_f32_16x16x32_f16(a1, b0, acc[1][0], 0, 0, 0);
      acc[1][1] = __builtin_amdgcn_mfma_f32_16x16x32_f16(a1, b1, acc[1][1], 0, 0, 0);
      acc[2][0] = __builtin_amdgcn_mfma_f32_16x16x32_f16(a2, b0, acc[2][0], 0, 0, 0);
      acc[2][1] = __builtin_amdgcn_mfma_f32_16x16x32_f16(a2, b1, acc[2][1], 0, 0, 0);
      acc[3][0] = __builtin_amdgcn_mfma_f32_16x16x32_f16(a3, b0, acc[3][0], 0, 0, 0);
      acc[3][1] = __builtin_amdgcn_mfma_f32_16x16x32_f16(a3, b1, acc[3][1], 0, 0, 0);
    }
  };

  // ---- c = Wy @ D^T (K=512), packed to f16 in registers ----
#pragma unroll
  for (int rt = 0; rt < 4; ++rt) acc[rt][0] = acc[rt][1] = (floatx4){0.f, 0.f, 0.f, 0.f};
  gemmK512(bufB, Df);
  half4 ch[4][2];
#pragma unroll
  for (int rt = 0; rt < 4; ++rt)
#pragma unroll
    for (int ct = 0; ct < 2; ++ct)
#pragma unroll
      for (int r = 0; r < 4; ++r) ch[rt][ct][r] = (_Float16)acc[rt][ct][r];

  // ---- zero d state + output slice 0 ----
  {
    int* za = reinterpret_cast<int*>(bufA);
    for (int i = tid; i < TB * LDP / 2; i += THREADS) za[i] = 0;
    float4 z4 = {0.f, 0.f, 0.f, 0.f};
    float4* o4 = reinterpret_cast<float4*>(out + (size_t)rowBase * N_SZ);
    for (int i = tid; i < TB * N_SZ / 4; i += THREADS) o4[i] = z4;
  }
  __syncthreads();

  const float thrv = *thrp;

#pragma unroll 1
  for (int it = 1; it <= NITER; ++it) {
    // ---- GEMM1: u = d @ E^T + c ; s = soft_thr(u) -> bufB ----
#pragma unroll
    for (int rt = 0; rt < 4; ++rt) acc[rt][0] = acc[rt][1] = (floatx4){0.f, 0.f, 0.f, 0.f};
    gemmK512(bufA, Ef);
#pragma unroll
    for (int rt = 0; rt < 4; ++rt)
#pragma unroll
      for (int ct = 0; ct < 2; ++ct)
#pragma unroll
        for (int r = 0; r < 4; ++r) {
          float u = acc[rt][ct][r] + (float)ch[rt][ct][r];
          float s = fmaxf(u - thrv, 0.f) - fmaxf(-u - thrv, 0.f);
          bufB[(rt * 16 + q * 4 + r) * LDP + colBase + ct * 16 + m16] = (_Float16)s;
        }
    __syncthreads();

    // ---- GEMM2: d' = s @ D -> bufA ----
#pragma unroll
    for (int rt = 0; rt < 4; ++rt) acc[rt][0] = acc[rt][1] = (floatx4){0.f, 0.f, 0.f, 0.f};
    gemmK512(bufB, Dtf);
#pragma unroll
    for (int rt = 0; rt < 4; ++rt)
#pragma unroll
      for (int ct = 0; ct < 2; ++ct)
#pragma unroll
        for (int r = 0; r < 4; ++r)
          bufA[(rt * 16 + q * 4 + r) * LDP + colBase + ct * 16 + m16] = (_Float16)acc[rt][ct][r];
    __syncthreads();

    // ---- vectorized copy-out of d' (f16 precision is well within threshold) ----
    float* oslice = out + ((size_t)it * B_SZ + rowBase) * N_SZ;
#pragma unroll
    for (int i = tid; i < TB * N_SZ / 8; i += THREADS) {
      int r = i >> 6;             // 64 8-elem chunks per row
      int c8 = (i & 63) << 3;
      half8 h = *reinterpret_cast<const half8*>(&bufA[r * LDP + c8]);
      float4 lo = {(float)h[0], (float)h[1], (float)h[2], (float)h[3]};
      float4 hi = {(float)h[4], (float)h[5], (float)h[6], (float)h[7]};
      float* dst = oslice + (size_t)r * N_SZ + c8;
      *reinterpret_cast<float4*>(dst) = lo;
      *reinterpret_cast<float4*>(dst + 4) = hi;
    }
  }
}

extern "C" void kernel_launch(void* const* d_in, const int* in_sizes, int n_in,
                              void* d_out, int out_size, void* d_ws, size_t ws_size,
                              hipStream_t stream) {
  const float* y = (const float*)d_in[0];
  const float* S = (const float*)d_in[1];
  const float* W = (const float*)d_in[2];
  const float* D = (const float*)d_in[3];
  const float* thr = (const float*)d_in[4];
  float* out = (float*)d_out;

  char* ws = (char*)d_ws;
  _Float16* Ef = (_Float16*)(ws);
  _Float16* Df = (_Float16*)(ws + 512 * 1024);
  _Float16* Dtf = (_Float16*)(ws + 1024 * 1024);
  _Float16* Wf = (_Float16*)(ws + 1536 * 1024);

  conv_kernel<<<(N_SZ * N_SZ + 255) / 256, 256, 0, stream>>>(W, D, Wf, Df, Dtf);
  ecomp_kernel<<<N_SZ / 8, 256, 0, stream>>>(S, D, Ef);
  ista_kernel<<<B_SZ / TB, THREADS, 0, stream>>>(y, Ef, Df, Dtf, Wf, thr, out);
}